// Round 2
// baseline (1120.493 us; speedup 1.0000x reference)
//
#include <hip/hip_runtime.h>
#include <cstdint>
#include <cstddef>

#define B_N   8
#define C_N   256
#define H_N   128
#define W_N   128
#define S_N   16384          // H*W
#define CS_N  4194304        // C*S
#define NELEM 33554432       // B*C*S
#define EPS_F 1e-5f

// ---------------------------------------------------------------------------
// Kernel 1: 1x1 conv as GEMM.  Y[b,o,s] = sum_c W[o,c] * X[b,c,s]
// tile 128(o) x 128(s), K-step 16, 8x8 micro-tile, fp32 LDS, fp32 accum.
// tensor 0: x_low*Wq -> qf (= d_out, fp32), tensor 1: x_high*Wk -> kf (= ws)
// ---------------------------------------------------------------------------
__global__ __launch_bounds__(256) void conv_gemm(
    const float* __restrict__ x_low, const float* __restrict__ x_high,
    const float* __restrict__ Wq, const float* __restrict__ Wk,
    float* __restrict__ qf, float* __restrict__ kf)
{
  const int tid = threadIdx.x;
  const int tx = tid & 15, ty = tid >> 4;
  const int s0 = blockIdx.x * 128;
  const int o0 = blockIdx.y * 128;
  const int tensor = blockIdx.z >> 3;
  const int b = blockIdx.z & 7;

  const float* __restrict__ X = tensor ? x_high : x_low;
  const float* __restrict__ Wm = tensor ? Wk : Wq;
  float* __restrict__ Y = tensor ? kf : qf;

  __shared__ float As[16][128];  // As[k][o]
  __shared__ float Bs[16][132];  // Bs[k][s], padded

  float acc[8][8];
#pragma unroll
  for (int i = 0; i < 8; ++i)
#pragma unroll
    for (int j = 0; j < 8; ++j) acc[i][j] = 0.0f;

  const size_t xbase = (size_t)b * CS_N;
  const int a_oo = tid >> 1;          // 0..127
  const int a_kk = (tid & 1) * 8;     // 0 or 8
  const int b_kk = tid >> 4;          // 0..15
  const int b_ss = (tid & 15) * 8;    // 0..120

  for (int k0 = 0; k0 < 256; k0 += 16) {
    __syncthreads();
    {
      const float* src = Wm + ((size_t)(o0 + a_oo) * 256 + k0 + a_kk);
      const float4 w0 = *reinterpret_cast<const float4*>(src);
      const float4 w1 = *reinterpret_cast<const float4*>(src + 4);
      As[a_kk + 0][a_oo] = w0.x; As[a_kk + 1][a_oo] = w0.y;
      As[a_kk + 2][a_oo] = w0.z; As[a_kk + 3][a_oo] = w0.w;
      As[a_kk + 4][a_oo] = w1.x; As[a_kk + 5][a_oo] = w1.y;
      As[a_kk + 6][a_oo] = w1.z; As[a_kk + 7][a_oo] = w1.w;
    }
    {
      const float* src = X + (xbase + (size_t)(k0 + b_kk) * S_N + s0 + b_ss);
      const float4 x0 = *reinterpret_cast<const float4*>(src);
      const float4 x1 = *reinterpret_cast<const float4*>(src + 4);
      Bs[b_kk][b_ss + 0] = x0.x; Bs[b_kk][b_ss + 1] = x0.y;
      Bs[b_kk][b_ss + 2] = x0.z; Bs[b_kk][b_ss + 3] = x0.w;
      Bs[b_kk][b_ss + 4] = x1.x; Bs[b_kk][b_ss + 5] = x1.y;
      Bs[b_kk][b_ss + 6] = x1.z; Bs[b_kk][b_ss + 7] = x1.w;
    }
    __syncthreads();
#pragma unroll
    for (int kk = 0; kk < 16; ++kk) {
      const float4 a0 = *reinterpret_cast<const float4*>(&As[kk][ty * 8]);
      const float4 a1 = *reinterpret_cast<const float4*>(&As[kk][ty * 8 + 4]);
      // split columns {4tx..4tx+3} and {64+4tx..64+4tx+3} -> 2-way banks (free)
      const float4 b0 = *reinterpret_cast<const float4*>(&Bs[kk][tx * 4]);
      const float4 b1 = *reinterpret_cast<const float4*>(&Bs[kk][64 + tx * 4]);
      const float av[8] = {a0.x, a0.y, a0.z, a0.w, a1.x, a1.y, a1.z, a1.w};
      const float bv[8] = {b0.x, b0.y, b0.z, b0.w, b1.x, b1.y, b1.z, b1.w};
#pragma unroll
      for (int i = 0; i < 8; ++i)
#pragma unroll
        for (int j = 0; j < 8; ++j) acc[i][j] = fmaf(av[i], bv[j], acc[i][j]);
    }
  }

#pragma unroll
  for (int i = 0; i < 8; ++i) {
    float* row = Y + (xbase + (size_t)(o0 + ty * 8 + i) * S_N + s0);
    *reinterpret_cast<float4*>(row + tx * 4) =
        make_float4(acc[i][0], acc[i][1], acc[i][2], acc[i][3]);
    *reinterpret_cast<float4*>(row + 64 + tx * 4) =
        make_float4(acc[i][4], acc[i][5], acc[i][6], acc[i][7]);
  }
}

// ---------------------------------------------------------------------------
// Kernel 2: GroupNorm stats. One block per (tensor, b, g).
// Group channels contiguous: 8*16384 fp32 elements.
// stats[tensor*256 + b*32 + g] = (mean, rsqrt(var+eps))
// ---------------------------------------------------------------------------
__global__ __launch_bounds__(256) void gn_stats(
    const float* __restrict__ qf, const float* __restrict__ kf,
    float2* __restrict__ stats)
{
  const int bid = blockIdx.x;            // 0..511
  const int tensor = bid >> 8;
  const int rem = bid & 255;
  const int b = rem >> 5;
  const int g = rem & 31;
  const float* __restrict__ base =
      (tensor ? kf : qf) + (size_t)b * CS_N + (size_t)g * 8 * S_N;
  const float4* __restrict__ base4 = reinterpret_cast<const float4*>(base);

  const int tid = threadIdx.x;
  float s1 = 0.0f, s2 = 0.0f;
  for (int i = tid; i < 32768; i += 256) {   // 131072 floats = 32768 float4
    const float4 u = base4[i];
    s1 += u.x + u.y + u.z + u.w;
    s2 += u.x * u.x + u.y * u.y + u.z * u.z + u.w * u.w;
  }
#pragma unroll
  for (int off = 32; off > 0; off >>= 1) {
    s1 += __shfl_down(s1, off);
    s2 += __shfl_down(s2, off);
  }
  __shared__ float r1[4], r2[4];
  const int wave = tid >> 6;
  if ((tid & 63) == 0) { r1[wave] = s1; r2[wave] = s2; }
  __syncthreads();
  if (tid == 0) {
    const float S1 = r1[0] + r1[1] + r1[2] + r1[3];
    const float S2 = r2[0] + r2[1] + r2[2] + r2[3];
    const float mean = S1 * (1.0f / 131072.0f);
    const float var = S2 * (1.0f / 131072.0f) - mean * mean;
    stats[bid] = make_float2(mean, rsqrtf(var + EPS_F));
  }
}

// ---------------------------------------------------------------------------
// Kernel 3: per-patch attention, GN folded into per-channel scale/shift.
// One block per patch (2048). S = (q^T k)/16 over 4 c-chunks of 64; softmax;
// out = attn @ k^T per chunk; epilogue adds x_low, writes fp32 to out.
// qf lives in d_out: each element is read (S phase) then overwritten (PV
// epilogue) by exactly one block -> no cross-block hazard.
// ---------------------------------------------------------------------------
__global__ __launch_bounds__(256) void attn_kernel(
    const float* __restrict__ x_low,
    const float* __restrict__ gq, const float* __restrict__ bq,
    const float* __restrict__ gk, const float* __restrict__ bk,
    const float* __restrict__ qf, const float* __restrict__ kf,
    const float2* __restrict__ stats, float* __restrict__ out)
{
  const int n = blockIdx.x;
  const int b = n >> 8;
  const int ph = (n >> 4) & 15;
  const int pw = n & 15;
  const int h0 = ph * 8, w0 = pw * 8;
  const int t = threadIdx.x;
  const int tx = t & 15, ty = t >> 4;
  const int p = t & 63;     // pixel id for load/store phases
  const int ci = t >> 6;    // 0..3

  __shared__ float q_ch[64][68];   // [pixel][c_local]; reused as out-stage
  __shared__ float k_ch[64][68];
  __shared__ float s_mat[64][68];  // S then exp(S-max) (p-major)
  __shared__ float red[4][64];
  __shared__ float rowstat[2][64]; // [0]=rowmax [1]=rowsum
  __shared__ float qsc[256], qsh[256], ksc[256], ksh[256];

  {
    const int c = t;
    const int g = c >> 3;
    const float2 sq = stats[b * 32 + g];
    const float2 sk = stats[256 + b * 32 + g];
    const float gs = gq[c] * sq.y;
    qsc[c] = gs; qsh[c] = bq[c] - sq.x * gs;
    const float ks = gk[c] * sk.y;
    ksc[c] = ks; ksh[c] = bk[c] - sk.x * ks;
  }

  const size_t pixoff =
      (size_t)b * CS_N + (size_t)(h0 + (p >> 3)) * W_N + (w0 + (p & 7));

  float accs[4][4];
#pragma unroll
  for (int i = 0; i < 4; ++i)
#pragma unroll
    for (int j = 0; j < 4; ++j) accs[i][j] = 0.0f;

  // ---- S accumulation over 4 channel chunks ----
  for (int chunk = 0; chunk < 4; ++chunk) {
    __syncthreads();
    for (int cl = ci; cl < 64; cl += 4) {
      const int c = chunk * 64 + cl;
      const size_t a = pixoff + (size_t)c * S_N;
      q_ch[p][cl] = qf[a] * qsc[c] + qsh[c];
      k_ch[p][cl] = kf[a] * ksc[c] + ksh[c];
    }
    __syncthreads();
#pragma unroll
    for (int c4 = 0; c4 < 64; c4 += 4) {
      float qa[4][4], ka[4][4];
#pragma unroll
      for (int i = 0; i < 4; ++i) {
        const float4 v = *reinterpret_cast<const float4*>(&q_ch[ty + 16 * i][c4]);
        qa[i][0] = v.x; qa[i][1] = v.y; qa[i][2] = v.z; qa[i][3] = v.w;
      }
#pragma unroll
      for (int j = 0; j < 4; ++j) {
        const float4 v = *reinterpret_cast<const float4*>(&k_ch[tx + 16 * j][c4]);
        ka[j][0] = v.x; ka[j][1] = v.y; ka[j][2] = v.z; ka[j][3] = v.w;
      }
#pragma unroll
      for (int i = 0; i < 4; ++i)
#pragma unroll
        for (int j = 0; j < 4; ++j)
          accs[i][j] += qa[i][0] * ka[j][0] + qa[i][1] * ka[j][1] +
                        qa[i][2] * ka[j][2] + qa[i][3] * ka[j][3];
    }
  }
#pragma unroll
  for (int i = 0; i < 4; ++i)
#pragma unroll
    for (int j = 0; j < 4; ++j)
      s_mat[ty + 16 * i][tx + 16 * j] = accs[i][j] * 0.0625f;  // / sqrt(256)
  __syncthreads();

  // ---- softmax over rows (r = pixel p), normalization deferred ----
  {
    float m = -3.0e38f;
#pragma unroll
    for (int cc = 0; cc < 16; ++cc) m = fmaxf(m, s_mat[p][ci * 16 + cc]);
    red[ci][p] = m;
    __syncthreads();
    if (t < 64)
      rowstat[0][t] = fmaxf(fmaxf(red[0][t], red[1][t]), fmaxf(red[2][t], red[3][t]));
    __syncthreads();
    const float rm = rowstat[0][p];
    float sum = 0.0f;
#pragma unroll
    for (int cc = 0; cc < 16; ++cc) {
      const float e = __expf(s_mat[p][ci * 16 + cc] - rm);
      s_mat[p][ci * 16 + cc] = e;
      sum += e;
    }
    red[ci][p] = sum;
    __syncthreads();
    if (t < 64) rowstat[1][t] = red[0][t] + red[1][t] + red[2][t] + red[3][t];
    __syncthreads();
  }
  const float rinv = 1.0f / rowstat[1][p];

  // ---- PV per channel chunk, staged through q_ch for coalesced writes ----
  for (int chunk = 0; chunk < 4; ++chunk) {
    __syncthreads();
    for (int cl = ci; cl < 64; cl += 4) {
      const int c = chunk * 64 + cl;
      k_ch[p][cl] = kf[pixoff + (size_t)c * S_N] * ksc[c] + ksh[c];
    }
    __syncthreads();
    float accp[4][4];
#pragma unroll
    for (int i = 0; i < 4; ++i)
#pragma unroll
      for (int j = 0; j < 4; ++j) accp[i][j] = 0.0f;
#pragma unroll
    for (int r4 = 0; r4 < 64; r4 += 4) {
      float aa[4][4], kb[4][4];
#pragma unroll
      for (int i = 0; i < 4; ++i) {
        const float4 v = *reinterpret_cast<const float4*>(&s_mat[ty + 16 * i][r4]);
        aa[i][0] = v.x; aa[i][1] = v.y; aa[i][2] = v.z; aa[i][3] = v.w;
      }
#pragma unroll
      for (int m = 0; m < 4; ++m) {
        const float4 v = *reinterpret_cast<const float4*>(&k_ch[r4 + m][tx * 4]);
        kb[m][0] = v.x; kb[m][1] = v.y; kb[m][2] = v.z; kb[m][3] = v.w;
      }
#pragma unroll
      for (int i = 0; i < 4; ++i)
#pragma unroll
        for (int j = 0; j < 4; ++j)
          accp[i][j] += aa[i][0] * kb[0][j] + aa[i][1] * kb[1][j] +
                        aa[i][2] * kb[2][j] + aa[i][3] * kb[3][j];
    }
    __syncthreads();
#pragma unroll
    for (int i = 0; i < 4; ++i)
      *reinterpret_cast<float4*>(&q_ch[ty + 16 * i][tx * 4]) =
          make_float4(accp[i][0], accp[i][1], accp[i][2], accp[i][3]);
    __syncthreads();
    for (int cl = ci; cl < 64; cl += 4) {
      const int c = chunk * 64 + cl;
      const size_t a = pixoff + (size_t)c * S_N;
      out[a] = q_ch[p][cl] * rinv + x_low[a];
    }
  }
}

// ---------------------------------------------------------------------------
extern "C" void kernel_launch(void* const* d_in, const int* in_sizes, int n_in,
                              void* d_out, int out_size, void* d_ws, size_t ws_size,
                              hipStream_t stream)
{
  const float* x_low  = (const float*)d_in[0];
  const float* x_high = (const float*)d_in[1];
  const float* Wq     = (const float*)d_in[2];
  const float* gq     = (const float*)d_in[3];
  const float* bq     = (const float*)d_in[4];
  const float* Wk     = (const float*)d_in[5];
  const float* gk     = (const float*)d_in[6];
  const float* bk     = (const float*)d_in[7];
  float* out = (float*)d_out;

  float* qf = out;                    // qf scratch lives in d_out (see attn_kernel)
  float* kf = (float*)d_ws;           // 128 MiB
  float2* stats = (float2*)((char*)d_ws + (size_t)NELEM * 4);  // 512 float2

  dim3 gconv(128, 2, 16);
  hipLaunchKernelGGL(conv_gemm, gconv, dim3(256), 0, stream,
                     x_low, x_high, Wq, Wk, qf, kf);
  hipLaunchKernelGGL(gn_stats, dim3(512), dim3(256), 0, stream, qf, kf, stats);
  hipLaunchKernelGGL(attn_kernel, dim3(2048), dim3(256), 0, stream,
                     x_low, gq, bq, gk, bk, qf, kf, stats, out);
}